// Round 5
// baseline (29811.163 us; speedup 1.0000x reference)
//
#include <hip/hip_runtime.h>
#include <hip/hip_bf16.h>

#define NPTS 16384
#define MCENT 4096
#define BCLD 2
#define FDIM 32
#define H1DIM 64
#define CODIM 128
#define KNBR 64
// largest fp32 <= 0.04 (float64) == fp32(0.04f) == 0.039999999105930328
#define R2CUT 0.04f

// Exact (numpy-order, contraction-free) squared distance: ((dx*dx+dy*dy)+dz*dz)
__device__ __forceinline__ float d2e(float ax, float ay, float az,
                                     float bx, float by, float bz) {
  float dx = __fsub_rn(ax, bx);
  float dy = __fsub_rn(ay, by);
  float dz = __fsub_rn(az, bz);
  return __fadd_rn(__fadd_rn(__fmul_rn(dx, dx), __fmul_rn(dy, dy)), __fmul_rn(dz, dz));
}

// 3-bit spread for 9-bit Morton
__device__ __forceinline__ int spread3(int v) {
  return ((v & 4) << 4) | ((v & 2) << 2) | (v & 1);
}
__device__ __forceinline__ int cell_of(float x, float y, float z) {
  int cx = min(7, (int)(x * 8.0f));
  int cy = min(7, (int)(y * 8.0f));
  int cz = min(7, (int)(z * 8.0f));
  return (spread3(cx) << 2) | (spread3(cy) << 1) | spread3(cz);
}

// Lexicographic max over (bits, nidx) pairs via DPP (VALU pipe — no LDS).
// Identity (0,0) can never beat a real candidate (real nidx = ~oidx > 0).
#define DPP_LEXMAX_STEP(bb, nn, ctrl)                                          \
  do {                                                                         \
    unsigned _ob = (unsigned)__builtin_amdgcn_update_dpp(0, (int)(bb), ctrl,   \
                                                         0xf, 0xf, false);     \
    unsigned _on = (unsigned)__builtin_amdgcn_update_dpp(0, (int)(nn), ctrl,   \
                                                         0xf, 0xf, false);     \
    bool _t = (_ob > (bb)) || (_ob == (bb) && _on > (nn));                     \
    (bb) = _t ? _ob : (bb);                                                    \
    (nn) = _t ? _on : (nn);                                                    \
  } while (0)

__device__ __forceinline__ int rdlane(int v, int l) {
  return __builtin_amdgcn_readlane(v, l);
}
__device__ __forceinline__ float rdlanef(float v, int l) {
  return __int_as_float(__builtin_amdgcn_readlane(__float_as_int(v), l));
}

// ---------------- Kernel 1: farthest point sampling (1 block per cloud) ----
// 256 threads (4 waves) x 64 pts, Morton-counting-sorted. Each thread keeps
// 4 sub-chunks of 16 pts with own bbox + max-key + best-pos: sharp per-sub
// prune (0.999 margin >> fp rounding), 16-pt update quantum. 4-wave barrier
// (1 wave/SIMD: minimal arrival skew), 4-slot parity LDS combine, DPP lexmax
// everywhere, no global ops in-loop. Selection sequence bit-identical to ref.
__global__ __launch_bounds__(256, 1) void fps_kernel(const float* __restrict__ pos,
                                                     int* __restrict__ fps_idx,
                                                     float4* __restrict__ ws_sorted) {
  const int b = blockIdx.x;
  const float* P = pos + (size_t)b * NPTS * 3;
  float4* S = ws_sorted + (size_t)b * NPTS;
  const int tid = threadIdx.x;
  const int lane = tid & 63;
  const int wave = tid >> 6;  // 0..3

  __shared__ int hist[512];
  __shared__ int offs[512];
  __shared__ unsigned long long skey[2][4];
  __shared__ float4 spos[2][4];
  __shared__ int winners[MCENT];

  // ---- phase A: counting sort by Morton cell into ws_sorted (global) ----
  hist[tid] = 0;
  hist[tid + 256] = 0;
  __syncthreads();
#pragma unroll 4
  for (int j = 0; j < 64; ++j) {
    int i = tid + j * 256;
    float x = P[3 * i + 0], y = P[3 * i + 1], z = P[3 * i + 2];
    atomicAdd(&hist[cell_of(x, y, z)], 1);
  }
  __syncthreads();
  if (tid < 64) {  // wave 0: exclusive scan of 512 cells
    int base = tid * 8;
    int loc[8];
    int run = 0;
#pragma unroll
    for (int k = 0; k < 8; ++k) { loc[k] = run; run += hist[base + k]; }
    int inc = run;
#pragma unroll
    for (int off = 1; off < 64; off <<= 1) {
      int o = __shfl_up(inc, off);
      if (tid >= off) inc += o;
    }
    int ex = inc - run;
#pragma unroll
    for (int k = 0; k < 8; ++k) offs[base + k] = ex + loc[k];
  }
  __syncthreads();
#pragma unroll 4
  for (int j = 0; j < 64; ++j) {
    int i = tid + j * 256;
    float x = P[3 * i + 0], y = P[3 * i + 1], z = P[3 * i + 2];
    int p = atomicAdd(&offs[cell_of(x, y, z)], 1);
    S[p] = make_float4(x, y, z, __int_as_float(i));
  }
  __syncthreads();  // global S writes drained before re-read (validated R2-R4)

  // ---- phase B: load 4x16-pt sub-chunks; init d vs original point 0 ----
  float px[64], py[64], pz[64], d[64];
  unsigned npk[32];  // packed low-16 of ~origidx (high 16 always 0xFFFF)
  unsigned long long skmax[4];           // per-sub max key (d_bits, ~idx)
  float sbxm[4], sbxM[4], sbym[4], sbyM[4], sbzm[4], sbzM[4];
  float spxr[4], spyr[4], spzr[4];       // per-sub best-pos
  const float x0 = P[0], y0 = P[1], z0 = P[2];

#pragma unroll
  for (int s = 0; s < 4; ++s) {
    unsigned sb = 0u, sn = 0u;
    float sx = 0.f, sy = 0.f, sz = 0.f;
    float xm = 1e30f, xM = -1e30f, ym = 1e30f, yM = -1e30f, zm = 1e30f, zM = -1e30f;
#pragma unroll
    for (int t = 0; t < 16; ++t) {
      const int j = s * 16 + t;
      float4 v = S[tid * 64 + j];
      px[j] = v.x; py[j] = v.y; pz[j] = v.z;
      unsigned nj = ~(unsigned)__float_as_int(v.w);
      if ((j & 1) == 0) npk[j >> 1] = nj & 0xFFFFu;
      else npk[j >> 1] |= (nj & 0xFFFFu) << 16;
      float dj = d2e(v.x, v.y, v.z, x0, y0, z0);
      d[j] = dj;
      xm = fminf(xm, v.x); xM = fmaxf(xM, v.x);
      ym = fminf(ym, v.y); yM = fmaxf(yM, v.y);
      zm = fminf(zm, v.z); zM = fmaxf(zM, v.z);
      unsigned db = __float_as_uint(dj);
      bool g = (db > sb) || (db == sb && nj > sn);
      sb = g ? db : sb; sn = g ? nj : sn;
      sx = g ? v.x : sx; sy = g ? v.y : sy; sz = g ? v.z : sz;
    }
    skmax[s] = ((unsigned long long)sb << 32) | sn;
    sbxm[s] = xm; sbxM[s] = xM; sbym[s] = ym; sbyM[s] = yM; sbzm[s] = zm; sbzM[s] = zM;
    spxr[s] = sx; spyr[s] = sy; spzr[s] = sz;
  }

  // thread key = lexmax over sub keys (track pos via selects, no dyn indexing)
  unsigned tkb, tkn;
  float tx, ty, tz;
  {
    unsigned long long k = skmax[0];
    float ax = spxr[0], ay = spyr[0], az = spzr[0];
#pragma unroll
    for (int s = 1; s < 4; ++s) {
      bool g = skmax[s] > k;
      k = g ? skmax[s] : k;
      ax = g ? spxr[s] : ax; ay = g ? spyr[s] : ay; az = g ? spzr[s] : az;
    }
    tkb = (unsigned)(k >> 32); tkn = (unsigned)k; tx = ax; ty = ay; tz = az;
  }

  if (tid == 0) winners[0] = 0;

  bool wavedirty = true;
  unsigned cwb = 0u, cwn = 0u;
  float cwx = 0.f, cwy = 0.f, cwz = 0.f;

  for (int m = 1; m < MCENT; ++m) {
    const int par = m & 1;

    if (wavedirty) {  // recompute wave winner via full-wave DPP lexmax
      unsigned bb = tkb, nn = tkn;
      DPP_LEXMAX_STEP(bb, nn, 0x111);  // row_shr:1
      DPP_LEXMAX_STEP(bb, nn, 0x112);  // row_shr:2
      DPP_LEXMAX_STEP(bb, nn, 0x114);  // row_shr:4
      DPP_LEXMAX_STEP(bb, nn, 0x118);  // row_shr:8
      DPP_LEXMAX_STEP(bb, nn, 0x142);  // row_bcast:15
      DPP_LEXMAX_STEP(bb, nn, 0x143);  // row_bcast:31
      cwb = (unsigned)rdlane((int)bb, 63);
      cwn = (unsigned)rdlane((int)nn, 63);
      unsigned long long own = __ballot(tkb == cwb && tkn == cwn);
      int ol = (int)__ffsll(own) - 1;  // unique: nidx carries a unique point id
      cwx = rdlanef(tx, ol);
      cwy = rdlanef(ty, ol);
      cwz = rdlanef(tz, ol);
    }
    if (lane == 0) {  // always republish (parity buffer alternates)
      skey[par][wave] = ((unsigned long long)cwb << 32) | (unsigned long long)cwn;
      spos[par][wave] = make_float4(cwx, cwy, cwz, 0.0f);
    }
    __syncthreads();  // 4 waves, 1/SIMD — minimal skew

    // cross-wave combine: lanes 0..3 take one slot each, 2-step DPP lexmax
    unsigned rb, rn;
    unsigned sb0 = 0u, sn0 = 0u;
    {
      unsigned bb = 0u, nn = 0u;
      if (lane < 4) {
        unsigned long long kk = skey[par][lane];
        bb = (unsigned)(kk >> 32);
        nn = (unsigned)kk;
        sb0 = bb; sn0 = nn;
        DPP_LEXMAX_STEP(bb, nn, 0x111);
        DPP_LEXMAX_STEP(bb, nn, 0x112);
      }
      rb = (unsigned)rdlane((int)bb, 3);
      rn = (unsigned)rdlane((int)nn, 3);
    }
    unsigned long long wm = __ballot(lane < 4 && sb0 == rb && sn0 == rn);
    int ws = (int)__ffsll(wm) - 1;   // winning slot (wave) id — unique key
    float4 wp = spos[par][ws];       // single b128 broadcast read
    if (tid == 0) winners[m] = (int)(~rn);

    // per-sub prune + update (16-pt quantum)
    bool mydirty = false;
#pragma unroll
    for (int s = 0; s < 4; ++s) {
      float ex = fmaxf(fmaxf(sbxm[s] - wp.x, wp.x - sbxM[s]), 0.0f);
      float ey = fmaxf(fmaxf(sbym[s] - wp.y, wp.y - sbyM[s]), 0.0f);
      float ez = fmaxf(fmaxf(sbzm[s] - wp.z, wp.z - sbzM[s]), 0.0f);
      float lb = (ex * ex + ey * ey + ez * ez) * 0.999f;
      if (lb < __uint_as_float((unsigned)(skmax[s] >> 32))) {
        mydirty = true;
        unsigned nb = 0u, nn2 = 0u;
        float nx = 0.f, ny = 0.f, nz = 0.f;
#pragma unroll
        for (int t = 0; t < 16; ++t) {
          const int j = s * 16 + t;
          float dj = fminf(d[j], d2e(px[j], py[j], pz[j], wp.x, wp.y, wp.z));
          d[j] = dj;
          unsigned db = __float_as_uint(dj);
          unsigned nj = 0xFFFF0000u | ((npk[j >> 1] >> ((j & 1) * 16)) & 0xFFFFu);
          bool g = (db > nb) || (db == nb && nj > nn2);
          nb = g ? db : nb; nn2 = g ? nj : nn2;
          nx = g ? px[j] : nx; ny = g ? py[j] : ny; nz = g ? pz[j] : nz;
        }
        skmax[s] = ((unsigned long long)nb << 32) | nn2;
        spxr[s] = nx; spyr[s] = ny; spzr[s] = nz;
      }
    }
    if (mydirty) {  // refresh thread key from sub keys
      unsigned long long k = skmax[0];
      float ax = spxr[0], ay = spyr[0], az = spzr[0];
#pragma unroll
      for (int s = 1; s < 4; ++s) {
        bool g = skmax[s] > k;
        k = g ? skmax[s] : k;
        ax = g ? spxr[s] : ax; ay = g ? spyr[s] : ay; az = g ? spzr[s] : az;
      }
      tkb = (unsigned)(k >> 32); tkn = (unsigned)k; tx = ax; ty = ay; tz = az;
    }
    wavedirty = (__ballot(mydirty) != 0ULL);
  }

  __syncthreads();
  for (int i = tid; i < MCENT; i += 256) fps_idx[b * MCENT + i] = winners[i];
}

// ------------- Kernel 2: ball query + K-smallest selection (1 wave/centroid) --
__global__ __launch_bounds__(256) void ballq_kernel(const float* __restrict__ pos,
                                                    const int* __restrict__ fps_idx,
                                                    int* __restrict__ nbr,
                                                    float* __restrict__ out_pc,
                                                    float* __restrict__ out_batch) {
  const int wave = threadIdx.x >> 6;
  const int lane = threadIdx.x & 63;
  const int c = blockIdx.x * 4 + wave;   // global centroid id
  const int b = c >> 12;                 // 4096 centroids per cloud
  const float* P = pos + (size_t)b * NPTS * 3;

  const int ci = fps_idx[c];
  const float cx = P[3 * ci + 0];
  const float cy = P[3 * ci + 1];
  const float cz = P[3 * ci + 2];
  if (lane == 0) {
    out_pc[3 * c + 0] = cx;
    out_pc[3 * c + 1] = cy;
    out_pc[3 * c + 2] = cz;
    out_batch[c] = (float)b;
  }

  __shared__ unsigned long long list[4][1024];
  __shared__ int cnt[4];
  if (lane == 0) cnt[wave] = 0;

  for (int i = lane; i < NPTS; i += 64) {
    const float qx = P[3 * i + 0];
    const float qy = P[3 * i + 1];
    const float qz = P[3 * i + 2];
    const float dd = d2e(cx, cy, cz, qx, qy, qz);
    if (dd <= R2CUT) {
      int p = atomicAdd(&cnt[wave], 1);
      if (p < 1024)
        list[wave][p] = ((unsigned long long)__float_as_uint(dd) << 32)
                      | (unsigned long long)(unsigned)i;
    }
  }
  __syncthreads();

  int n = cnt[wave];
  if (n > 1024) n = 1024;

  unsigned long long loc[16];
#pragma unroll
  for (int k = 0; k < 16; ++k) {
    int i = lane + k * 64;
    loc[k] = (i < n) ? list[wave][i] : ~0ULL;
  }
  unsigned long long mv = loc[0];
#pragma unroll
  for (int k = 1; k < 16; ++k)
    if (loc[k] < mv) mv = loc[k];

  int myout = -1;
  for (int s = 0; s < 64; ++s) {
    unsigned long long wmin = mv;
#pragma unroll
    for (int off = 32; off >= 1; off >>= 1) {
      unsigned long long o = __shfl_xor(wmin, off);
      if (o < wmin) wmin = o;
    }
    if (lane == s) myout = (wmin == ~0ULL) ? -1 : (int)(unsigned)wmin;
    if (mv == wmin && wmin != ~0ULL) {
#pragma unroll
      for (int k = 0; k < 16; ++k)
        if (loc[k] == wmin) loc[k] = ~0ULL;
      mv = loc[0];
#pragma unroll
      for (int k = 1; k < 16; ++k)
        if (loc[k] < mv) mv = loc[k];
    }
  }
  nbr[c * KNBR + lane] = myout;
}

// ------------- Kernel 3: MLP (35->64 relu ->128) + masked max-pool ----------
__global__ __launch_bounds__(256) void mlp_kernel(const float* __restrict__ pos,
                                                  const float* __restrict__ x,
                                                  const int* __restrict__ fps_idx,
                                                  const int* __restrict__ nbr,
                                                  const float* __restrict__ W1,
                                                  const float* __restrict__ b1,
                                                  const float* __restrict__ W2,
                                                  const float* __restrict__ b2,
                                                  float* __restrict__ out) {
  const int c = blockIdx.x;
  const int b = c >> 12;
  const float* P = pos + (size_t)b * NPTS * 3;
  const float* X = x + (size_t)b * NPTS * FDIM;

  __shared__ float W1s[35 * 64];
  __shared__ float W2s[64 * 128];
  __shared__ float b1s[64];
  __shared__ float b2s[128];
  __shared__ float h1s[64][64];
  __shared__ float pmax[2][128];
  __shared__ int validk[64];

  const int tid = threadIdx.x;
  for (int i = tid; i < 35 * 64; i += 256) W1s[i] = W1[i];
  for (int i = tid; i < 64 * 128; i += 256) W2s[i] = W2[i];
  if (tid < 64) b1s[tid] = b1[tid];
  else if (tid < 192) b2s[tid - 64] = b2[tid - 64];

  const int ci = fps_idx[c];
  const float c5x = P[3 * ci + 0] / 0.2f;  // faithful: pos_i / r
  const float c5y = P[3 * ci + 1] / 0.2f;
  const float c5z = P[3 * ci + 2] / 0.2f;

  const int k = tid >> 2, q = tid & 3;
  const int nk = nbr[c * KNBR + k];
  if (q == 0) validk[k] = (nk >= 0) ? 1 : 0;
  const int nkc = (nk < 0) ? 0 : nk;

  float msg[35];
  const float4* Xr = (const float4*)(X + (size_t)nkc * FDIM);
#pragma unroll
  for (int i4 = 0; i4 < 8; ++i4) {
    float4 v = Xr[i4];
    msg[i4 * 4 + 0] = v.x; msg[i4 * 4 + 1] = v.y;
    msg[i4 * 4 + 2] = v.z; msg[i4 * 4 + 3] = v.w;
  }
  msg[32] = P[3 * nkc + 0] - c5x;
  msg[33] = P[3 * nkc + 1] - c5y;
  msg[34] = P[3 * nkc + 2] - c5z;

  __syncthreads();

  float acc[16];
#pragma unroll
  for (int h = 0; h < 16; ++h) acc[h] = b1s[q * 16 + h];
#pragma unroll
  for (int i = 0; i < 35; ++i) {
    const float m = msg[i];
    const float4* wrow = (const float4*)&W1s[i * 64 + q * 16];
#pragma unroll
    for (int j4 = 0; j4 < 4; ++j4) {
      float4 w = wrow[j4];
      acc[j4 * 4 + 0] += m * w.x;
      acc[j4 * 4 + 1] += m * w.y;
      acc[j4 * 4 + 2] += m * w.z;
      acc[j4 * 4 + 3] += m * w.w;
    }
  }
#pragma unroll
  for (int h = 0; h < 16; ++h) h1s[k][q * 16 + h] = fmaxf(acc[h], 0.0f);
  __syncthreads();

  const int ch = tid & 127, half = tid >> 7;
  float w2r[64];
#pragma unroll
  for (int i = 0; i < 64; ++i) w2r[i] = W2s[i * 128 + ch];

  float mx = -INFINITY;
  for (int k2 = half * 32; k2 < half * 32 + 32; ++k2) {
    if (!validk[k2]) continue;
    float s = b2s[ch];
    const float4* hr = (const float4*)h1s[k2];
#pragma unroll
    for (int i4 = 0; i4 < 16; ++i4) {
      float4 h4 = hr[i4];
      s += h4.x * w2r[i4 * 4 + 0] + h4.y * w2r[i4 * 4 + 1]
         + h4.z * w2r[i4 * 4 + 2] + h4.w * w2r[i4 * 4 + 3];
    }
    mx = fmaxf(mx, s);
  }
  pmax[half][ch] = mx;
  __syncthreads();

  if (tid < 128) {
    float m2 = fmaxf(pmax[0][tid], pmax[1][tid]);
    out[(size_t)c * CODIM + tid] = (m2 > -INFINITY) ? m2 : 0.0f;
  }
}

extern "C" void kernel_launch(void* const* d_in, const int* in_sizes, int n_in,
                              void* d_out, int out_size, void* d_ws, size_t ws_size,
                              hipStream_t stream) {
  const float* x   = (const float*)d_in[0];
  const float* pos = (const float*)d_in[1];
  const float* W1  = (const float*)d_in[3];
  const float* b1  = (const float*)d_in[4];
  const float* W2  = (const float*)d_in[5];
  const float* b2  = (const float*)d_in[6];
  float* out = (float*)d_out;

  int* fps_idx = (int*)d_ws;                  // B*M ints = 32 KiB
  int* nbr     = (int*)d_ws + BCLD * MCENT;   // B*M*K ints = 2 MiB
  // fps scratch aliases the nbr region (fps completes before ballq writes nbr)
  float4* ws_sorted = (float4*)nbr;           // B*N float4 = 512 KiB

  float* out_pc    = out + (size_t)BCLD * MCENT * CODIM;
  float* out_batch = out_pc + (size_t)BCLD * MCENT * 3;

  hipLaunchKernelGGL(fps_kernel, dim3(BCLD), dim3(256), 0, stream, pos, fps_idx, ws_sorted);
  hipLaunchKernelGGL(ballq_kernel, dim3(BCLD * MCENT / 4), dim3(256), 0, stream,
                     pos, fps_idx, nbr, out_pc, out_batch);
  hipLaunchKernelGGL(mlp_kernel, dim3(BCLD * MCENT), dim3(256), 0, stream,
                     pos, x, fps_idx, nbr, W1, b1, W2, b2, out);
}

// Round 6
// 13329.231 us; speedup vs baseline: 2.2365x; 2.2365x over previous
//
#include <hip/hip_runtime.h>
#include <hip/hip_bf16.h>

#define NPTS 16384
#define MCENT 4096
#define BCLD 2
#define FDIM 32
#define H1DIM 64
#define CODIM 128
#define KNBR 64
// largest fp32 <= 0.04 (float64) == fp32(0.04f) == 0.039999999105930328
#define R2CUT 0.04f

// Exact (numpy-order, contraction-free) squared distance: ((dx*dx+dy*dy)+dz*dz)
__device__ __forceinline__ float d2e(float ax, float ay, float az,
                                     float bx, float by, float bz) {
  float dx = __fsub_rn(ax, bx);
  float dy = __fsub_rn(ay, by);
  float dz = __fsub_rn(az, bz);
  return __fadd_rn(__fadd_rn(__fmul_rn(dx, dx), __fmul_rn(dy, dy)), __fmul_rn(dz, dz));
}

// 3-bit spread for 9-bit Morton
__device__ __forceinline__ int spread3(int v) {
  return ((v & 4) << 4) | ((v & 2) << 2) | (v & 1);
}
__device__ __forceinline__ int cell_of(float x, float y, float z) {
  int cx = min(7, (int)(x * 8.0f));
  int cy = min(7, (int)(y * 8.0f));
  int cz = min(7, (int)(z * 8.0f));
  return (spread3(cx) << 2) | (spread3(cy) << 1) | spread3(cz);
}

// Lexicographic max over (bits, nidx) pairs via DPP (VALU pipe — no LDS).
// Identity (0,0) can never beat a real candidate (real nidx = ~oidx > 0).
#define DPP_LEXMAX_STEP(bb, nn, ctrl)                                          \
  do {                                                                         \
    unsigned _ob = (unsigned)__builtin_amdgcn_update_dpp(0, (int)(bb), ctrl,   \
                                                         0xf, 0xf, false);     \
    unsigned _on = (unsigned)__builtin_amdgcn_update_dpp(0, (int)(nn), ctrl,   \
                                                         0xf, 0xf, false);     \
    bool _t = (_ob > (bb)) || (_ob == (bb) && _on > (nn));                     \
    (bb) = _t ? _ob : (bb);                                                    \
    (nn) = _t ? _on : (nn);                                                    \
  } while (0)

__device__ __forceinline__ int rdlane(int v, int l) {
  return __builtin_amdgcn_readlane(v, l);
}
__device__ __forceinline__ float rdlanef(float v, int l) {
  return __int_as_float(__builtin_amdgcn_readlane(__float_as_int(v), l));
}

// ---------------- Kernel 1: farthest point sampling (1 block per cloud) ----
// 512 threads (8 waves) x 32 pts (2 sub-chunks of 16), Morton-counting-sorted.
// ONLY d[32] is register-resident; positions are re-read from the sorted
// global array S on the dirty path (L2-resident, pipelined dwordx4) — keeps
// per-thread registers ~90 (no AGPR churn, no scratch; R5's spill lesson).
// Per-sub bbox prune (0.999 margin >> fp rounding), DPP lexmax reductions,
// 8-slot parity LDS combine, ONE barrier/iter, no global stores in-loop.
// Selection sequence bit-identical to ref.
__global__ __launch_bounds__(512, 1) void fps_kernel(const float* __restrict__ pos,
                                                     int* __restrict__ fps_idx,
                                                     float4* __restrict__ ws_sorted) {
  const int b = blockIdx.x;
  const float* P = pos + (size_t)b * NPTS * 3;
  float4* S = ws_sorted + (size_t)b * NPTS;
  const int tid = threadIdx.x;
  const int lane = tid & 63;
  const int wave = tid >> 6;  // 0..7

  __shared__ int hist[512];
  __shared__ int offs[512];
  __shared__ unsigned long long skey[2][8];
  __shared__ float4 spos[2][8];
  __shared__ int winners[MCENT];

  // ---- phase A: counting sort by Morton cell into ws_sorted (global) ----
  hist[tid] = 0;
  __syncthreads();
#pragma unroll 4
  for (int j = 0; j < 32; ++j) {
    int i = tid + j * 512;
    float x = P[3 * i + 0], y = P[3 * i + 1], z = P[3 * i + 2];
    atomicAdd(&hist[cell_of(x, y, z)], 1);
  }
  __syncthreads();
  if (tid < 64) {  // wave 0: exclusive scan of 512 cells
    int base = tid * 8;
    int loc[8];
    int run = 0;
#pragma unroll
    for (int k = 0; k < 8; ++k) { loc[k] = run; run += hist[base + k]; }
    int inc = run;
#pragma unroll
    for (int off = 1; off < 64; off <<= 1) {
      int o = __shfl_up(inc, off);
      if (tid >= off) inc += o;
    }
    int ex = inc - run;
#pragma unroll
    for (int k = 0; k < 8; ++k) offs[base + k] = ex + loc[k];
  }
  __syncthreads();
#pragma unroll 4
  for (int j = 0; j < 32; ++j) {
    int i = tid + j * 512;
    float x = P[3 * i + 0], y = P[3 * i + 1], z = P[3 * i + 2];
    int p = atomicAdd(&offs[cell_of(x, y, z)], 1);
    S[p] = make_float4(x, y, z, __int_as_float(i));
  }
  __syncthreads();  // global S writes drained before re-read (validated R2-R4)

  // ---- phase B: stream 2x16-pt sub-chunks; d in VGPR, meta per sub ----
  float d[32];
  unsigned long long skmax[2];              // per-sub max key (d_bits, ~idx)
  float sbxm[2], sbxM[2], sbym[2], sbyM[2], sbzm[2], sbzM[2];
  float spxr[2], spyr[2], spzr[2];          // per-sub best-pos
  const float x0 = P[0], y0 = P[1], z0 = P[2];

#pragma unroll
  for (int s = 0; s < 2; ++s) {
    unsigned sb = 0u, sn = 0u;
    float sx = 0.f, sy = 0.f, sz = 0.f;
    float xm = 1e30f, xM = -1e30f, ym = 1e30f, yM = -1e30f, zm = 1e30f, zM = -1e30f;
#pragma unroll
    for (int t = 0; t < 16; ++t) {
      const int j = s * 16 + t;
      float4 v = S[tid * 32 + j];
      float dj = d2e(v.x, v.y, v.z, x0, y0, z0);
      d[j] = dj;
      xm = fminf(xm, v.x); xM = fmaxf(xM, v.x);
      ym = fminf(ym, v.y); yM = fmaxf(yM, v.y);
      zm = fminf(zm, v.z); zM = fmaxf(zM, v.z);
      unsigned db = __float_as_uint(dj);
      unsigned nj = ~(unsigned)__float_as_int(v.w);
      bool g = (db > sb) || (db == sb && nj > sn);
      sb = g ? db : sb; sn = g ? nj : sn;
      sx = g ? v.x : sx; sy = g ? v.y : sy; sz = g ? v.z : sz;
    }
    skmax[s] = ((unsigned long long)sb << 32) | sn;
    sbxm[s] = xm; sbxM[s] = xM; sbym[s] = ym; sbyM[s] = yM; sbzm[s] = zm; sbzM[s] = zM;
    spxr[s] = sx; spyr[s] = sy; spzr[s] = sz;
  }

  if (tid == 0) winners[0] = 0;

  bool wavedirty = true;
  unsigned cwb = 0u, cwn = 0u;
  float cwx = 0.f, cwy = 0.f, cwz = 0.f;

  for (int m = 1; m < MCENT; ++m) {
    const int par = m & 1;

    if (wavedirty) {  // thread key from 2 subs, then full-wave DPP lexmax
      bool g2 = skmax[1] > skmax[0];
      unsigned long long k = g2 ? skmax[1] : skmax[0];
      unsigned tkb = (unsigned)(k >> 32), tkn = (unsigned)k;
      float tx = g2 ? spxr[1] : spxr[0];
      float ty = g2 ? spyr[1] : spyr[0];
      float tz = g2 ? spzr[1] : spzr[0];
      unsigned bb = tkb, nn = tkn;
      DPP_LEXMAX_STEP(bb, nn, 0x111);  // row_shr:1
      DPP_LEXMAX_STEP(bb, nn, 0x112);  // row_shr:2
      DPP_LEXMAX_STEP(bb, nn, 0x114);  // row_shr:4
      DPP_LEXMAX_STEP(bb, nn, 0x118);  // row_shr:8
      DPP_LEXMAX_STEP(bb, nn, 0x142);  // row_bcast:15
      DPP_LEXMAX_STEP(bb, nn, 0x143);  // row_bcast:31
      cwb = (unsigned)rdlane((int)bb, 63);
      cwn = (unsigned)rdlane((int)nn, 63);
      unsigned long long own = __ballot(tkb == cwb && tkn == cwn);
      int ol = (int)__ffsll(own) - 1;  // unique: nidx carries a unique point id
      cwx = rdlanef(tx, ol);
      cwy = rdlanef(ty, ol);
      cwz = rdlanef(tz, ol);
    }
    if (lane == 0) {  // always republish (parity buffer alternates)
      skey[par][wave] = ((unsigned long long)cwb << 32) | (unsigned long long)cwn;
      spos[par][wave] = make_float4(cwx, cwy, cwz, 0.0f);
    }
    __syncthreads();

    // cross-wave combine: lanes 0..7 take one slot each, 3-step DPP lexmax
    unsigned rb, rn;
    unsigned sb0 = 0u, sn0 = 0u;
    {
      unsigned bb = 0u, nn = 0u;
      if (lane < 8) {
        unsigned long long kk = skey[par][lane];
        bb = (unsigned)(kk >> 32);
        nn = (unsigned)kk;
        sb0 = bb; sn0 = nn;
        DPP_LEXMAX_STEP(bb, nn, 0x111);
        DPP_LEXMAX_STEP(bb, nn, 0x112);
        DPP_LEXMAX_STEP(bb, nn, 0x114);
      }
      rb = (unsigned)rdlane((int)bb, 7);
      rn = (unsigned)rdlane((int)nn, 7);
    }
    unsigned long long wm = __ballot(lane < 8 && sb0 == rb && sn0 == rn);
    int ws = (int)__ffsll(wm) - 1;   // winning slot (wave) id — unique key
    float4 wp = spos[par][ws];       // single b128 broadcast read
    if (tid == 0) winners[m] = (int)(~rn);

    // per-sub prune + update; positions reloaded from S (L2) on dirty path
    bool mydirty = false;
#pragma unroll
    for (int s = 0; s < 2; ++s) {
      float ex = fmaxf(fmaxf(sbxm[s] - wp.x, wp.x - sbxM[s]), 0.0f);
      float ey = fmaxf(fmaxf(sbym[s] - wp.y, wp.y - sbyM[s]), 0.0f);
      float ez = fmaxf(fmaxf(sbzm[s] - wp.z, wp.z - sbzM[s]), 0.0f);
      float lb = (ex * ex + ey * ey + ez * ez) * 0.999f;
      if (lb < __uint_as_float((unsigned)(skmax[s] >> 32))) {
        mydirty = true;
        const float4* Sp = S + (size_t)tid * 32 + s * 16;
        unsigned nb = 0u, nn2 = 0u;
        float nx = 0.f, ny = 0.f, nz = 0.f;
#pragma unroll
        for (int t = 0; t < 16; ++t) {
          const int j = s * 16 + t;
          float4 v = Sp[t];
          float dj = fminf(d[j], d2e(v.x, v.y, v.z, wp.x, wp.y, wp.z));
          d[j] = dj;
          unsigned db = __float_as_uint(dj);
          unsigned nj = ~(unsigned)__float_as_int(v.w);
          bool g = (db > nb) || (db == nb && nj > nn2);
          nb = g ? db : nb; nn2 = g ? nj : nn2;
          nx = g ? v.x : nx; ny = g ? v.y : ny; nz = g ? v.z : nz;
        }
        skmax[s] = ((unsigned long long)nb << 32) | nn2;
        spxr[s] = nx; spyr[s] = ny; spzr[s] = nz;
      }
    }
    wavedirty = (__ballot(mydirty) != 0ULL);
  }

  __syncthreads();
  for (int i = tid; i < MCENT; i += 512) fps_idx[b * MCENT + i] = winners[i];
}

// ------------- Kernel 2: ball query + K-smallest selection (1 wave/centroid) --
__global__ __launch_bounds__(256) void ballq_kernel(const float* __restrict__ pos,
                                                    const int* __restrict__ fps_idx,
                                                    int* __restrict__ nbr,
                                                    float* __restrict__ out_pc,
                                                    float* __restrict__ out_batch) {
  const int wave = threadIdx.x >> 6;
  const int lane = threadIdx.x & 63;
  const int c = blockIdx.x * 4 + wave;   // global centroid id
  const int b = c >> 12;                 // 4096 centroids per cloud
  const float* P = pos + (size_t)b * NPTS * 3;

  const int ci = fps_idx[c];
  const float cx = P[3 * ci + 0];
  const float cy = P[3 * ci + 1];
  const float cz = P[3 * ci + 2];
  if (lane == 0) {
    out_pc[3 * c + 0] = cx;
    out_pc[3 * c + 1] = cy;
    out_pc[3 * c + 2] = cz;
    out_batch[c] = (float)b;
  }

  __shared__ unsigned long long list[4][1024];
  __shared__ int cnt[4];
  if (lane == 0) cnt[wave] = 0;

  for (int i = lane; i < NPTS; i += 64) {
    const float qx = P[3 * i + 0];
    const float qy = P[3 * i + 1];
    const float qz = P[3 * i + 2];
    const float dd = d2e(cx, cy, cz, qx, qy, qz);
    if (dd <= R2CUT) {
      int p = atomicAdd(&cnt[wave], 1);
      if (p < 1024)
        list[wave][p] = ((unsigned long long)__float_as_uint(dd) << 32)
                      | (unsigned long long)(unsigned)i;
    }
  }
  __syncthreads();

  int n = cnt[wave];
  if (n > 1024) n = 1024;

  unsigned long long loc[16];
#pragma unroll
  for (int k = 0; k < 16; ++k) {
    int i = lane + k * 64;
    loc[k] = (i < n) ? list[wave][i] : ~0ULL;
  }
  unsigned long long mv = loc[0];
#pragma unroll
  for (int k = 1; k < 16; ++k)
    if (loc[k] < mv) mv = loc[k];

  int myout = -1;
  for (int s = 0; s < 64; ++s) {
    unsigned long long wmin = mv;
#pragma unroll
    for (int off = 32; off >= 1; off >>= 1) {
      unsigned long long o = __shfl_xor(wmin, off);
      if (o < wmin) wmin = o;
    }
    if (lane == s) myout = (wmin == ~0ULL) ? -1 : (int)(unsigned)wmin;
    if (mv == wmin && wmin != ~0ULL) {
#pragma unroll
      for (int k = 0; k < 16; ++k)
        if (loc[k] == wmin) loc[k] = ~0ULL;
      mv = loc[0];
#pragma unroll
      for (int k = 1; k < 16; ++k)
        if (loc[k] < mv) mv = loc[k];
    }
  }
  nbr[c * KNBR + lane] = myout;
}

// ------------- Kernel 3: MLP (35->64 relu ->128) + masked max-pool ----------
__global__ __launch_bounds__(256) void mlp_kernel(const float* __restrict__ pos,
                                                  const float* __restrict__ x,
                                                  const int* __restrict__ fps_idx,
                                                  const int* __restrict__ nbr,
                                                  const float* __restrict__ W1,
                                                  const float* __restrict__ b1,
                                                  const float* __restrict__ W2,
                                                  const float* __restrict__ b2,
                                                  float* __restrict__ out) {
  const int c = blockIdx.x;
  const int b = c >> 12;
  const float* P = pos + (size_t)b * NPTS * 3;
  const float* X = x + (size_t)b * NPTS * FDIM;

  __shared__ float W1s[35 * 64];
  __shared__ float W2s[64 * 128];
  __shared__ float b1s[64];
  __shared__ float b2s[128];
  __shared__ float h1s[64][64];
  __shared__ float pmax[2][128];
  __shared__ int validk[64];

  const int tid = threadIdx.x;
  for (int i = tid; i < 35 * 64; i += 256) W1s[i] = W1[i];
  for (int i = tid; i < 64 * 128; i += 256) W2s[i] = W2[i];
  if (tid < 64) b1s[tid] = b1[tid];
  else if (tid < 192) b2s[tid - 64] = b2[tid - 64];

  const int ci = fps_idx[c];
  const float c5x = P[3 * ci + 0] / 0.2f;  // faithful: pos_i / r
  const float c5y = P[3 * ci + 1] / 0.2f;
  const float c5z = P[3 * ci + 2] / 0.2f;

  const int k = tid >> 2, q = tid & 3;
  const int nk = nbr[c * KNBR + k];
  if (q == 0) validk[k] = (nk >= 0) ? 1 : 0;
  const int nkc = (nk < 0) ? 0 : nk;

  float msg[35];
  const float4* Xr = (const float4*)(X + (size_t)nkc * FDIM);
#pragma unroll
  for (int i4 = 0; i4 < 8; ++i4) {
    float4 v = Xr[i4];
    msg[i4 * 4 + 0] = v.x; msg[i4 * 4 + 1] = v.y;
    msg[i4 * 4 + 2] = v.z; msg[i4 * 4 + 3] = v.w;
  }
  msg[32] = P[3 * nkc + 0] - c5x;
  msg[33] = P[3 * nkc + 1] - c5y;
  msg[34] = P[3 * nkc + 2] - c5z;

  __syncthreads();

  float acc[16];
#pragma unroll
  for (int h = 0; h < 16; ++h) acc[h] = b1s[q * 16 + h];
#pragma unroll
  for (int i = 0; i < 35; ++i) {
    const float m = msg[i];
    const float4* wrow = (const float4*)&W1s[i * 64 + q * 16];
#pragma unroll
    for (int j4 = 0; j4 < 4; ++j4) {
      float4 w = wrow[j4];
      acc[j4 * 4 + 0] += m * w.x;
      acc[j4 * 4 + 1] += m * w.y;
      acc[j4 * 4 + 2] += m * w.z;
      acc[j4 * 4 + 3] += m * w.w;
    }
  }
#pragma unroll
  for (int h = 0; h < 16; ++h) h1s[k][q * 16 + h] = fmaxf(acc[h], 0.0f);
  __syncthreads();

  const int ch = tid & 127, half = tid >> 7;
  float w2r[64];
#pragma unroll
  for (int i = 0; i < 64; ++i) w2r[i] = W2s[i * 128 + ch];

  float mx = -INFINITY;
  for (int k2 = half * 32; k2 < half * 32 + 32; ++k2) {
    if (!validk[k2]) continue;
    float s = b2s[ch];
    const float4* hr = (const float4*)h1s[k2];
#pragma unroll
    for (int i4 = 0; i4 < 16; ++i4) {
      float4 h4 = hr[i4];
      s += h4.x * w2r[i4 * 4 + 0] + h4.y * w2r[i4 * 4 + 1]
         + h4.z * w2r[i4 * 4 + 2] + h4.w * w2r[i4 * 4 + 3];
    }
    mx = fmaxf(mx, s);
  }
  pmax[half][ch] = mx;
  __syncthreads();

  if (tid < 128) {
    float m2 = fmaxf(pmax[0][tid], pmax[1][tid]);
    out[(size_t)c * CODIM + tid] = (m2 > -INFINITY) ? m2 : 0.0f;
  }
}

extern "C" void kernel_launch(void* const* d_in, const int* in_sizes, int n_in,
                              void* d_out, int out_size, void* d_ws, size_t ws_size,
                              hipStream_t stream) {
  const float* x   = (const float*)d_in[0];
  const float* pos = (const float*)d_in[1];
  const float* W1  = (const float*)d_in[3];
  const float* b1  = (const float*)d_in[4];
  const float* W2  = (const float*)d_in[5];
  const float* b2  = (const float*)d_in[6];
  float* out = (float*)d_out;

  int* fps_idx = (int*)d_ws;                  // B*M ints = 32 KiB
  int* nbr     = (int*)d_ws + BCLD * MCENT;   // B*M*K ints = 2 MiB
  // fps scratch aliases the nbr region (fps completes before ballq writes nbr)
  float4* ws_sorted = (float4*)nbr;           // B*N float4 = 512 KiB

  float* out_pc    = out + (size_t)BCLD * MCENT * CODIM;
  float* out_batch = out_pc + (size_t)BCLD * MCENT * 3;

  hipLaunchKernelGGL(fps_kernel, dim3(BCLD), dim3(512), 0, stream, pos, fps_idx, ws_sorted);
  hipLaunchKernelGGL(ballq_kernel, dim3(BCLD * MCENT / 4), dim3(256), 0, stream,
                     pos, fps_idx, nbr, out_pc, out_batch);
  hipLaunchKernelGGL(mlp_kernel, dim3(BCLD * MCENT), dim3(256), 0, stream,
                     pos, x, fps_idx, nbr, W1, b1, W2, b2, out);
}

// Round 7
// 12593.590 us; speedup vs baseline: 2.3672x; 1.0584x over previous
//
#include <hip/hip_runtime.h>
#include <hip/hip_bf16.h>

#define NPTS 16384
#define MCENT 4096
#define BCLD 2
#define FDIM 32
#define H1DIM 64
#define CODIM 128
#define KNBR 64
// largest fp32 <= 0.04 (float64) == fp32(0.04f) == 0.039999999105930328
#define R2CUT 0.04f

// Exact (numpy-order, contraction-free) squared distance: ((dx*dx+dy*dy)+dz*dz)
__device__ __forceinline__ float d2e(float ax, float ay, float az,
                                     float bx, float by, float bz) {
  float dx = __fsub_rn(ax, bx);
  float dy = __fsub_rn(ay, by);
  float dz = __fsub_rn(az, bz);
  return __fadd_rn(__fadd_rn(__fmul_rn(dx, dx), __fmul_rn(dy, dy)), __fmul_rn(dz, dz));
}

// 3-bit spread for 9-bit Morton
__device__ __forceinline__ int spread3(int v) {
  return ((v & 4) << 4) | ((v & 2) << 2) | (v & 1);
}
__device__ __forceinline__ int cell_of(float x, float y, float z) {
  int cx = min(7, (int)(x * 8.0f));
  int cy = min(7, (int)(y * 8.0f));
  int cz = min(7, (int)(z * 8.0f));
  return (spread3(cx) << 2) | (spread3(cy) << 1) | spread3(cz);
}

// Lexicographic max over (bits, nidx) pairs via DPP (VALU pipe — no LDS).
// Identity (0,0) can never beat a real candidate (real nidx = ~oidx > 0).
#define DPP_LEXMAX_STEP(bb, nn, ctrl)                                          \
  do {                                                                         \
    unsigned _ob = (unsigned)__builtin_amdgcn_update_dpp(0, (int)(bb), ctrl,   \
                                                         0xf, 0xf, false);     \
    unsigned _on = (unsigned)__builtin_amdgcn_update_dpp(0, (int)(nn), ctrl,   \
                                                         0xf, 0xf, false);     \
    bool _t = (_ob > (bb)) || (_ob == (bb) && _on > (nn));                     \
    (bb) = _t ? _ob : (bb);                                                    \
    (nn) = _t ? _on : (nn);                                                    \
  } while (0)

__device__ __forceinline__ int rdlane(int v, int l) {
  return __builtin_amdgcn_readlane(v, l);
}
__device__ __forceinline__ float rdlanef(float v, int l) {
  return __int_as_float(__builtin_amdgcn_readlane(__float_as_int(v), l));
}

// ---------------- Kernel 1: farthest point sampling (1 block per cloud) ----
// 512 threads (8 waves, 2/SIMD) x 32 pts in TRUE VGPRs (~200 < 256 cap from
// __launch_bounds__(512,2)): R4 showed AGPR-split churn ~doubles dirty cost,
// R5 showed >256 demand spills to scratch, R6 showed global reload adds
// ~3700 cyc/iter of serial latency. Morton-sorted 2x16-pt sub-chunks with
// per-sub bbox prune (0.999 margin >> fp rounding); DPP lexmax reductions;
// 8-slot parity LDS combine; ONE barrier/iter; no global ops in-loop.
// Selection sequence bit-identical to ref.
__global__ __launch_bounds__(512, 2) void fps_kernel(const float* __restrict__ pos,
                                                     int* __restrict__ fps_idx,
                                                     float4* __restrict__ ws_sorted) {
  const int b = blockIdx.x;
  const float* P = pos + (size_t)b * NPTS * 3;
  float4* S = ws_sorted + (size_t)b * NPTS;
  const int tid = threadIdx.x;
  const int lane = tid & 63;
  const int wave = tid >> 6;  // 0..7

  __shared__ int hist[512];
  __shared__ int offs[512];
  __shared__ unsigned long long skey[2][8];
  __shared__ float4 spos[2][8];
  __shared__ int winners[MCENT];

  // ---- phase A: counting sort by Morton cell into ws_sorted (global) ----
  hist[tid] = 0;
  __syncthreads();
#pragma unroll 4
  for (int j = 0; j < 32; ++j) {
    int i = tid + j * 512;
    float x = P[3 * i + 0], y = P[3 * i + 1], z = P[3 * i + 2];
    atomicAdd(&hist[cell_of(x, y, z)], 1);
  }
  __syncthreads();
  if (tid < 64) {  // wave 0: exclusive scan of 512 cells
    int base = tid * 8;
    int loc[8];
    int run = 0;
#pragma unroll
    for (int k = 0; k < 8; ++k) { loc[k] = run; run += hist[base + k]; }
    int inc = run;
#pragma unroll
    for (int off = 1; off < 64; off <<= 1) {
      int o = __shfl_up(inc, off);
      if (tid >= off) inc += o;
    }
    int ex = inc - run;
#pragma unroll
    for (int k = 0; k < 8; ++k) offs[base + k] = ex + loc[k];
  }
  __syncthreads();
#pragma unroll 4
  for (int j = 0; j < 32; ++j) {
    int i = tid + j * 512;
    float x = P[3 * i + 0], y = P[3 * i + 1], z = P[3 * i + 2];
    int p = atomicAdd(&offs[cell_of(x, y, z)], 1);
    S[p] = make_float4(x, y, z, __int_as_float(i));
  }
  __syncthreads();  // global S writes drained before re-read (validated R2-R4)

  // ---- phase B: load 2x16-pt sub-chunks into VGPRs; init d vs point 0 ----
  float px[32], py[32], pz[32], d[32];
  unsigned nj[32];                          // ~original_index (tiebreak)
  unsigned long long skmax[2];              // per-sub max key (d_bits, ~idx)
  float sbxm[2], sbxM[2], sbym[2], sbyM[2], sbzm[2], sbzM[2];
  float spxr[2], spyr[2], spzr[2];          // per-sub best-pos
  const float x0 = P[0], y0 = P[1], z0 = P[2];

#pragma unroll
  for (int s = 0; s < 2; ++s) {
    unsigned sb = 0u, sn = 0u;
    float sx = 0.f, sy = 0.f, sz = 0.f;
    float xm = 1e30f, xM = -1e30f, ym = 1e30f, yM = -1e30f, zm = 1e30f, zM = -1e30f;
#pragma unroll
    for (int t = 0; t < 16; ++t) {
      const int j = s * 16 + t;
      float4 v = S[tid * 32 + j];
      px[j] = v.x; py[j] = v.y; pz[j] = v.z;
      nj[j] = ~(unsigned)__float_as_int(v.w);
      float dj = d2e(v.x, v.y, v.z, x0, y0, z0);
      d[j] = dj;
      xm = fminf(xm, v.x); xM = fmaxf(xM, v.x);
      ym = fminf(ym, v.y); yM = fmaxf(yM, v.y);
      zm = fminf(zm, v.z); zM = fmaxf(zM, v.z);
      unsigned db = __float_as_uint(dj);
      bool g = (db > sb) || (db == sb && nj[j] > sn);
      sb = g ? db : sb; sn = g ? nj[j] : sn;
      sx = g ? v.x : sx; sy = g ? v.y : sy; sz = g ? v.z : sz;
    }
    skmax[s] = ((unsigned long long)sb << 32) | sn;
    sbxm[s] = xm; sbxM[s] = xM; sbym[s] = ym; sbyM[s] = yM; sbzm[s] = zm; sbzM[s] = zM;
    spxr[s] = sx; spyr[s] = sy; spzr[s] = sz;
  }

  if (tid == 0) winners[0] = 0;

  bool wavedirty = true;
  unsigned cwb = 0u, cwn = 0u;
  float cwx = 0.f, cwy = 0.f, cwz = 0.f;

  for (int m = 1; m < MCENT; ++m) {
    const int par = m & 1;

    if (wavedirty) {  // thread key from 2 subs, then full-wave DPP lexmax
      bool g2 = skmax[1] > skmax[0];
      unsigned long long k = g2 ? skmax[1] : skmax[0];
      unsigned tkb = (unsigned)(k >> 32), tkn = (unsigned)k;
      float tx = g2 ? spxr[1] : spxr[0];
      float ty = g2 ? spyr[1] : spyr[0];
      float tz = g2 ? spzr[1] : spzr[0];
      unsigned bb = tkb, nn = tkn;
      DPP_LEXMAX_STEP(bb, nn, 0x111);  // row_shr:1
      DPP_LEXMAX_STEP(bb, nn, 0x112);  // row_shr:2
      DPP_LEXMAX_STEP(bb, nn, 0x114);  // row_shr:4
      DPP_LEXMAX_STEP(bb, nn, 0x118);  // row_shr:8
      DPP_LEXMAX_STEP(bb, nn, 0x142);  // row_bcast:15
      DPP_LEXMAX_STEP(bb, nn, 0x143);  // row_bcast:31
      cwb = (unsigned)rdlane((int)bb, 63);
      cwn = (unsigned)rdlane((int)nn, 63);
      unsigned long long own = __ballot(tkb == cwb && tkn == cwn);
      int ol = (int)__ffsll(own) - 1;  // unique: nidx carries a unique point id
      cwx = rdlanef(tx, ol);
      cwy = rdlanef(ty, ol);
      cwz = rdlanef(tz, ol);
    }
    if (lane == 0) {  // always republish (parity buffer alternates)
      skey[par][wave] = ((unsigned long long)cwb << 32) | (unsigned long long)cwn;
      spos[par][wave] = make_float4(cwx, cwy, cwz, 0.0f);
    }
    __syncthreads();

    // cross-wave combine: lanes 0..7 take one slot each, 3-step DPP lexmax
    unsigned rb, rn;
    unsigned sb0 = 0u, sn0 = 0u;
    {
      unsigned bb = 0u, nn = 0u;
      if (lane < 8) {
        unsigned long long kk = skey[par][lane];
        bb = (unsigned)(kk >> 32);
        nn = (unsigned)kk;
        sb0 = bb; sn0 = nn;
        DPP_LEXMAX_STEP(bb, nn, 0x111);
        DPP_LEXMAX_STEP(bb, nn, 0x112);
        DPP_LEXMAX_STEP(bb, nn, 0x114);
      }
      rb = (unsigned)rdlane((int)bb, 7);
      rn = (unsigned)rdlane((int)nn, 7);
    }
    unsigned long long wm = __ballot(lane < 8 && sb0 == rb && sn0 == rn);
    int ws = (int)__ffsll(wm) - 1;   // winning slot (wave) id — unique key
    float4 wp = spos[par][ws];       // single b128 broadcast read
    if (tid == 0) winners[m] = (int)(~rn);

    // per-sub prune + update (register-resident, 16-pt quantum)
    bool mydirty = false;
#pragma unroll
    for (int s = 0; s < 2; ++s) {
      float ex = fmaxf(fmaxf(sbxm[s] - wp.x, wp.x - sbxM[s]), 0.0f);
      float ey = fmaxf(fmaxf(sbym[s] - wp.y, wp.y - sbyM[s]), 0.0f);
      float ez = fmaxf(fmaxf(sbzm[s] - wp.z, wp.z - sbzM[s]), 0.0f);
      float lb = (ex * ex + ey * ey + ez * ez) * 0.999f;
      if (lb < __uint_as_float((unsigned)(skmax[s] >> 32))) {
        mydirty = true;
        unsigned nb = 0u, nn2 = 0u;
        float nx = 0.f, ny = 0.f, nz = 0.f;
#pragma unroll
        for (int t = 0; t < 16; ++t) {
          const int j = s * 16 + t;
          float dj = fminf(d[j], d2e(px[j], py[j], pz[j], wp.x, wp.y, wp.z));
          d[j] = dj;
          unsigned db = __float_as_uint(dj);
          bool g = (db > nb) || (db == nb && nj[j] > nn2);
          nb = g ? db : nb; nn2 = g ? nj[j] : nn2;
          nx = g ? px[j] : nx; ny = g ? py[j] : ny; nz = g ? pz[j] : nz;
        }
        skmax[s] = ((unsigned long long)nb << 32) | nn2;
        spxr[s] = nx; spyr[s] = ny; spzr[s] = nz;
      }
    }
    wavedirty = (__ballot(mydirty) != 0ULL);
  }

  __syncthreads();
  for (int i = tid; i < MCENT; i += 512) fps_idx[b * MCENT + i] = winners[i];
}

// ------------- Kernel 2: ball query + K-smallest selection (1 wave/centroid) --
__global__ __launch_bounds__(256) void ballq_kernel(const float* __restrict__ pos,
                                                    const int* __restrict__ fps_idx,
                                                    int* __restrict__ nbr,
                                                    float* __restrict__ out_pc,
                                                    float* __restrict__ out_batch) {
  const int wave = threadIdx.x >> 6;
  const int lane = threadIdx.x & 63;
  const int c = blockIdx.x * 4 + wave;   // global centroid id
  const int b = c >> 12;                 // 4096 centroids per cloud
  const float* P = pos + (size_t)b * NPTS * 3;

  const int ci = fps_idx[c];
  const float cx = P[3 * ci + 0];
  const float cy = P[3 * ci + 1];
  const float cz = P[3 * ci + 2];
  if (lane == 0) {
    out_pc[3 * c + 0] = cx;
    out_pc[3 * c + 1] = cy;
    out_pc[3 * c + 2] = cz;
    out_batch[c] = (float)b;
  }

  __shared__ unsigned long long list[4][1024];
  __shared__ int cnt[4];
  if (lane == 0) cnt[wave] = 0;

  for (int i = lane; i < NPTS; i += 64) {
    const float qx = P[3 * i + 0];
    const float qy = P[3 * i + 1];
    const float qz = P[3 * i + 2];
    const float dd = d2e(cx, cy, cz, qx, qy, qz);
    if (dd <= R2CUT) {
      int p = atomicAdd(&cnt[wave], 1);
      if (p < 1024)
        list[wave][p] = ((unsigned long long)__float_as_uint(dd) << 32)
                      | (unsigned long long)(unsigned)i;
    }
  }
  __syncthreads();

  int n = cnt[wave];
  if (n > 1024) n = 1024;

  unsigned long long loc[16];
#pragma unroll
  for (int k = 0; k < 16; ++k) {
    int i = lane + k * 64;
    loc[k] = (i < n) ? list[wave][i] : ~0ULL;
  }
  unsigned long long mv = loc[0];
#pragma unroll
  for (int k = 1; k < 16; ++k)
    if (loc[k] < mv) mv = loc[k];

  int myout = -1;
  for (int s = 0; s < 64; ++s) {
    unsigned long long wmin = mv;
#pragma unroll
    for (int off = 32; off >= 1; off >>= 1) {
      unsigned long long o = __shfl_xor(wmin, off);
      if (o < wmin) wmin = o;
    }
    if (lane == s) myout = (wmin == ~0ULL) ? -1 : (int)(unsigned)wmin;
    if (mv == wmin && wmin != ~0ULL) {
#pragma unroll
      for (int k = 0; k < 16; ++k)
        if (loc[k] == wmin) loc[k] = ~0ULL;
      mv = loc[0];
#pragma unroll
      for (int k = 1; k < 16; ++k)
        if (loc[k] < mv) mv = loc[k];
    }
  }
  nbr[c * KNBR + lane] = myout;
}

// ------------- Kernel 3: MLP (35->64 relu ->128) + masked max-pool ----------
__global__ __launch_bounds__(256) void mlp_kernel(const float* __restrict__ pos,
                                                  const float* __restrict__ x,
                                                  const int* __restrict__ fps_idx,
                                                  const int* __restrict__ nbr,
                                                  const float* __restrict__ W1,
                                                  const float* __restrict__ b1,
                                                  const float* __restrict__ W2,
                                                  const float* __restrict__ b2,
                                                  float* __restrict__ out) {
  const int c = blockIdx.x;
  const int b = c >> 12;
  const float* P = pos + (size_t)b * NPTS * 3;
  const float* X = x + (size_t)b * NPTS * FDIM;

  __shared__ float W1s[35 * 64];
  __shared__ float W2s[64 * 128];
  __shared__ float b1s[64];
  __shared__ float b2s[128];
  __shared__ float h1s[64][64];
  __shared__ float pmax[2][128];
  __shared__ int validk[64];

  const int tid = threadIdx.x;
  for (int i = tid; i < 35 * 64; i += 256) W1s[i] = W1[i];
  for (int i = tid; i < 64 * 128; i += 256) W2s[i] = W2[i];
  if (tid < 64) b1s[tid] = b1[tid];
  else if (tid < 192) b2s[tid - 64] = b2[tid - 64];

  const int ci = fps_idx[c];
  const float c5x = P[3 * ci + 0] / 0.2f;  // faithful: pos_i / r
  const float c5y = P[3 * ci + 1] / 0.2f;
  const float c5z = P[3 * ci + 2] / 0.2f;

  const int k = tid >> 2, q = tid & 3;
  const int nk = nbr[c * KNBR + k];
  if (q == 0) validk[k] = (nk >= 0) ? 1 : 0;
  const int nkc = (nk < 0) ? 0 : nk;

  float msg[35];
  const float4* Xr = (const float4*)(X + (size_t)nkc * FDIM);
#pragma unroll
  for (int i4 = 0; i4 < 8; ++i4) {
    float4 v = Xr[i4];
    msg[i4 * 4 + 0] = v.x; msg[i4 * 4 + 1] = v.y;
    msg[i4 * 4 + 2] = v.z; msg[i4 * 4 + 3] = v.w;
  }
  msg[32] = P[3 * nkc + 0] - c5x;
  msg[33] = P[3 * nkc + 1] - c5y;
  msg[34] = P[3 * nkc + 2] - c5z;

  __syncthreads();

  float acc[16];
#pragma unroll
  for (int h = 0; h < 16; ++h) acc[h] = b1s[q * 16 + h];
#pragma unroll
  for (int i = 0; i < 35; ++i) {
    const float m = msg[i];
    const float4* wrow = (const float4*)&W1s[i * 64 + q * 16];
#pragma unroll
    for (int j4 = 0; j4 < 4; ++j4) {
      float4 w = wrow[j4];
      acc[j4 * 4 + 0] += m * w.x;
      acc[j4 * 4 + 1] += m * w.y;
      acc[j4 * 4 + 2] += m * w.z;
      acc[j4 * 4 + 3] += m * w.w;
    }
  }
#pragma unroll
  for (int h = 0; h < 16; ++h) h1s[k][q * 16 + h] = fmaxf(acc[h], 0.0f);
  __syncthreads();

  const int ch = tid & 127, half = tid >> 7;
  float w2r[64];
#pragma unroll
  for (int i = 0; i < 64; ++i) w2r[i] = W2s[i * 128 + ch];

  float mx = -INFINITY;
  for (int k2 = half * 32; k2 < half * 32 + 32; ++k2) {
    if (!validk[k2]) continue;
    float s = b2s[ch];
    const float4* hr = (const float4*)h1s[k2];
#pragma unroll
    for (int i4 = 0; i4 < 16; ++i4) {
      float4 h4 = hr[i4];
      s += h4.x * w2r[i4 * 4 + 0] + h4.y * w2r[i4 * 4 + 1]
         + h4.z * w2r[i4 * 4 + 2] + h4.w * w2r[i4 * 4 + 3];
    }
    mx = fmaxf(mx, s);
  }
  pmax[half][ch] = mx;
  __syncthreads();

  if (tid < 128) {
    float m2 = fmaxf(pmax[0][tid], pmax[1][tid]);
    out[(size_t)c * CODIM + tid] = (m2 > -INFINITY) ? m2 : 0.0f;
  }
}

extern "C" void kernel_launch(void* const* d_in, const int* in_sizes, int n_in,
                              void* d_out, int out_size, void* d_ws, size_t ws_size,
                              hipStream_t stream) {
  const float* x   = (const float*)d_in[0];
  const float* pos = (const float*)d_in[1];
  const float* W1  = (const float*)d_in[3];
  const float* b1  = (const float*)d_in[4];
  const float* W2  = (const float*)d_in[5];
  const float* b2  = (const float*)d_in[6];
  float* out = (float*)d_out;

  int* fps_idx = (int*)d_ws;                  // B*M ints = 32 KiB
  int* nbr     = (int*)d_ws + BCLD * MCENT;   // B*M*K ints = 2 MiB
  // fps scratch aliases the nbr region (fps completes before ballq writes nbr)
  float4* ws_sorted = (float4*)nbr;           // B*N float4 = 512 KiB

  float* out_pc    = out + (size_t)BCLD * MCENT * CODIM;
  float* out_batch = out_pc + (size_t)BCLD * MCENT * 3;

  hipLaunchKernelGGL(fps_kernel, dim3(BCLD), dim3(512), 0, stream, pos, fps_idx, ws_sorted);
  hipLaunchKernelGGL(ballq_kernel, dim3(BCLD * MCENT / 4), dim3(256), 0, stream,
                     pos, fps_idx, nbr, out_pc, out_batch);
  hipLaunchKernelGGL(mlp_kernel, dim3(BCLD * MCENT), dim3(256), 0, stream,
                     pos, x, fps_idx, nbr, W1, b1, W2, b2, out);
}

// Round 8
// 9700.858 us; speedup vs baseline: 3.0730x; 1.2982x over previous
//
#include <hip/hip_runtime.h>
#include <hip/hip_bf16.h>

#define NPTS 16384
#define MCENT 4096
#define BCLD 2
#define FDIM 32
#define H1DIM 64
#define CODIM 128
#define KNBR 64
// largest fp32 <= 0.04 (float64) == fp32(0.04f) == 0.039999999105930328
#define R2CUT 0.04f

// Exact (numpy-order, contraction-free) squared distance: ((dx*dx+dy*dy)+dz*dz)
__device__ __forceinline__ float d2e(float ax, float ay, float az,
                                     float bx, float by, float bz) {
  float dx = __fsub_rn(ax, bx);
  float dy = __fsub_rn(ay, by);
  float dz = __fsub_rn(az, bz);
  return __fadd_rn(__fadd_rn(__fmul_rn(dx, dx), __fmul_rn(dy, dy)), __fmul_rn(dz, dz));
}

// 3-bit spread for 9-bit Morton
__device__ __forceinline__ int spread3(int v) {
  return ((v & 4) << 4) | ((v & 2) << 2) | (v & 1);
}
__device__ __forceinline__ int cell_of(float x, float y, float z) {
  int cx = min(7, (int)(x * 8.0f));
  int cy = min(7, (int)(y * 8.0f));
  int cz = min(7, (int)(z * 8.0f));
  return (spread3(cx) << 2) | (spread3(cy) << 1) | spread3(cz);
}

// Lexicographic max over (hi,lo) u32 pairs via DPP (VALU pipe — no LDS).
// Identity (0,0) can never beat a real candidate (real lo = ~oidx > 0).
#define DPP_LEXMAX_STEP(bb, nn, ctrl)                                          \
  do {                                                                         \
    unsigned _ob = (unsigned)__builtin_amdgcn_update_dpp(0, (int)(bb), ctrl,   \
                                                         0xf, 0xf, false);     \
    unsigned _on = (unsigned)__builtin_amdgcn_update_dpp(0, (int)(nn), ctrl,   \
                                                         0xf, 0xf, false);     \
    bool _t = (_ob > (bb)) || (_ob == (bb) && _on > (nn));                     \
    (bb) = _t ? _ob : (bb);                                                    \
    (nn) = _t ? _on : (nn);                                                    \
  } while (0)

// Same, carrying a 3rd payload register (slot id) with the winner.
#define DPP_LEXMAX3_STEP(bb, nn, vv, ctrl)                                     \
  do {                                                                         \
    unsigned _ob = (unsigned)__builtin_amdgcn_update_dpp(0, (int)(bb), ctrl,   \
                                                         0xf, 0xf, false);     \
    unsigned _on = (unsigned)__builtin_amdgcn_update_dpp(0, (int)(nn), ctrl,   \
                                                         0xf, 0xf, false);     \
    int _ov = __builtin_amdgcn_update_dpp(0, (int)(vv), ctrl, 0xf, 0xf, false);\
    bool _t = (_ob > (bb)) || (_ob == (bb) && _on > (nn));                     \
    (bb) = _t ? _ob : (bb);                                                    \
    (nn) = _t ? _on : (nn);                                                    \
    (vv) = _t ? _ov : (vv);                                                    \
  } while (0)

__device__ __forceinline__ int rdlane(int v, int l) {
  return __builtin_amdgcn_readlane(v, l);
}
__device__ __forceinline__ float rdlanef(float v, int l) {
  return __int_as_float(__builtin_amdgcn_readlane(__float_as_int(v), l));
}

// ---------------- Kernel 1: farthest point sampling (1 block per cloud) ----
// R4-proven skeleton: 1024 threads (16 waves, 4/SIMD — the TLP hides the
// serial DPP/LDS chains; R6/R7 showed 8 waves is 2x WORSE) x 16 Morton-sorted
// pts/thread, per-thread bbox prune (0.999 margin >> fp rounding).
// R8 changes: __launch_bounds__(1024,4) declares the 128-reg/wave budget so
// arrays live in TRUE VGPRs (R4 reported VGPR=64 => arch/accum split + AGPR
// churn on every dirty access); u64 keys (v_cmp_lt_u64 shortens the select
// chain); one-LDS-read combine with slot-id carried through DPP (second
// serial LDS read + ballot removed from the critical path).
// Selection sequence bit-identical to ref.
__global__ __launch_bounds__(1024, 4) void fps_kernel(const float* __restrict__ pos,
                                                      int* __restrict__ fps_idx,
                                                      float4* __restrict__ ws_sorted) {
  const int b = blockIdx.x;
  const float* P = pos + (size_t)b * NPTS * 3;
  float4* S = ws_sorted + (size_t)b * NPTS;
  const int tid = threadIdx.x;
  const int lane = tid & 63;
  const int wave = tid >> 6;  // 0..15

  __shared__ int hist[512];
  __shared__ int offs[512];
  __shared__ float4 sA[2][16];  // {key.lo, key.hi, x, y} per wave
  __shared__ float sZ[2][16];   // z per wave
  __shared__ int winners[MCENT];

  // ---- phase A: counting sort by Morton cell into ws_sorted (global) ----
  if (tid < 512) hist[tid] = 0;
  __syncthreads();
#pragma unroll 4
  for (int j = 0; j < 16; ++j) {
    int i = tid + j * 1024;
    float x = P[3 * i + 0], y = P[3 * i + 1], z = P[3 * i + 2];
    atomicAdd(&hist[cell_of(x, y, z)], 1);
  }
  __syncthreads();
  if (tid < 64) {  // wave 0: exclusive scan of 512 cells
    int base = tid * 8;
    int loc[8];
    int run = 0;
#pragma unroll
    for (int k = 0; k < 8; ++k) { loc[k] = run; run += hist[base + k]; }
    int inc = run;
#pragma unroll
    for (int off = 1; off < 64; off <<= 1) {
      int o = __shfl_up(inc, off);
      if (tid >= off) inc += o;
    }
    int ex = inc - run;
#pragma unroll
    for (int k = 0; k < 8; ++k) offs[base + k] = ex + loc[k];
  }
  __syncthreads();
#pragma unroll 4
  for (int j = 0; j < 16; ++j) {
    int i = tid + j * 1024;
    float x = P[3 * i + 0], y = P[3 * i + 1], z = P[3 * i + 2];
    int p = atomicAdd(&offs[cell_of(x, y, z)], 1);
    S[p] = make_float4(x, y, z, __int_as_float(i));
  }
  __syncthreads();  // global S writes drained before re-read (validated R2-R4)

  // ---- phase B: load 16-pt chunk into VGPRs; init d vs original point 0 ----
  float px[16], py[16], pz[16], d[16];
  unsigned nidx[16];  // ~original_index (tiebreak payload)
  const float x0 = P[0], y0 = P[1], z0 = P[2];
  float bxm, bxM, bym, byM, bzm, bzM;
  unsigned long long tk = 0ull;        // thread-best key (d_bits, ~idx)
  float tx = 0.f, ty = 0.f, tz = 0.f;  // thread-best position
#pragma unroll
  for (int j = 0; j < 16; ++j) {
    float4 v = S[tid * 16 + j];
    px[j] = v.x; py[j] = v.y; pz[j] = v.z;
    nidx[j] = ~(unsigned)__float_as_int(v.w);
    float dj = d2e(v.x, v.y, v.z, x0, y0, z0);
    d[j] = dj;
    if (j == 0) {
      bxm = v.x; bxM = v.x; bym = v.y; byM = v.y; bzm = v.z; bzM = v.z;
    } else {
      bxm = fminf(bxm, v.x); bxM = fmaxf(bxM, v.x);
      bym = fminf(bym, v.y); byM = fmaxf(byM, v.y);
      bzm = fminf(bzm, v.z); bzM = fmaxf(bzM, v.z);
    }
    unsigned long long cand = ((unsigned long long)__float_as_uint(dj) << 32)
                            | (unsigned long long)nidx[j];
    bool g = cand > tk;
    tk = g ? cand : tk;
    tx = g ? v.x : tx; ty = g ? v.y : ty; tz = g ? v.z : tz;
  }

  if (tid == 0) winners[0] = 0;

  bool wavedirty = true;
  unsigned long long cwk = 0ull;         // cached wave-winner key
  float cwx = 0.f, cwy = 0.f, cwz = 0.f; // cached wave-winner pos

  for (int m = 1; m < MCENT; ++m) {
    const int par = m & 1;

    if (wavedirty) {  // recompute wave winner via full-wave DPP lexmax
      unsigned bb = (unsigned)(tk >> 32), nn = (unsigned)tk;
      DPP_LEXMAX_STEP(bb, nn, 0x111);  // row_shr:1
      DPP_LEXMAX_STEP(bb, nn, 0x112);  // row_shr:2
      DPP_LEXMAX_STEP(bb, nn, 0x114);  // row_shr:4
      DPP_LEXMAX_STEP(bb, nn, 0x118);  // row_shr:8
      DPP_LEXMAX_STEP(bb, nn, 0x142);  // row_bcast:15
      DPP_LEXMAX_STEP(bb, nn, 0x143);  // row_bcast:31
      cwk = ((unsigned long long)(unsigned)rdlane((int)bb, 63) << 32)
          | (unsigned long long)(unsigned)rdlane((int)nn, 63);
      unsigned long long own = __ballot(tk == cwk);
      int ol = (int)__ffsll(own) - 1;  // unique: key carries a unique point id
      cwx = rdlanef(tx, ol);
      cwy = rdlanef(ty, ol);
      cwz = rdlanef(tz, ol);
    }
    if (lane == 0) {  // always republish (parity buffer alternates)
      sA[par][wave] = make_float4(__uint_as_float((unsigned)cwk),
                                  __uint_as_float((unsigned)(cwk >> 32)),
                                  cwx, cwy);
      sZ[par][wave] = cwz;
    }
    __syncthreads();

    // cross-wave combine: lanes 0..15 read one b128 slot each; DPP lexmax
    // carries the slot id; winner pos via 3 uniform readlanes (no 2nd LDS
    // read, no ballot on the critical path).
    unsigned bb = 0u, nn = 0u;
    int wv = 0;
    float vx = 0.f, vy = 0.f, vz = 0.f;
    if (lane < 16) {
      float4 a = sA[par][lane];
      nn = __float_as_uint(a.x);
      bb = __float_as_uint(a.y);
      vx = a.z; vy = a.w;
      vz = sZ[par][lane];
      wv = lane;
    }
    DPP_LEXMAX3_STEP(bb, nn, wv, 0x111);
    DPP_LEXMAX3_STEP(bb, nn, wv, 0x112);
    DPP_LEXMAX3_STEP(bb, nn, wv, 0x114);
    DPP_LEXMAX3_STEP(bb, nn, wv, 0x118);
    const int ws = rdlane(wv, 15);       // winning wave/slot id (uniform)
    const unsigned rn = (unsigned)rdlane((int)nn, 15);
    const float wx = rdlanef(vx, ws);
    const float wy = rdlanef(vy, ws);
    const float wz = rdlanef(vz, ws);
    if (tid == 0) winners[m] = (int)(~rn);

    // prune: lower-bound distance from winner to chunk bbox
    float ex = fmaxf(fmaxf(bxm - wx, wx - bxM), 0.0f);
    float ey = fmaxf(fmaxf(bym - wy, wy - byM), 0.0f);
    float ez = fmaxf(fmaxf(bzm - wz, wz - bzM), 0.0f);
    float lb = (ex * ex + ey * ey + ez * ez) * 0.999f;
    bool mydirty = lb < __uint_as_float((unsigned)(tk >> 32));
    if (mydirty) {
      unsigned long long nk = 0ull;
      float nx = 0.f, ny = 0.f, nz = 0.f;
#pragma unroll
      for (int j = 0; j < 16; ++j) {
        float dj = fminf(d[j], d2e(px[j], py[j], pz[j], wx, wy, wz));
        d[j] = dj;
        unsigned long long cand = ((unsigned long long)__float_as_uint(dj) << 32)
                                | (unsigned long long)nidx[j];
        bool g = cand > nk;
        nk = g ? cand : nk;
        nx = g ? px[j] : nx; ny = g ? py[j] : ny; nz = g ? pz[j] : nz;
      }
      tk = nk; tx = nx; ty = ny; tz = nz;
    }
    wavedirty = (__ballot(mydirty) != 0ULL);
  }

  __syncthreads();
  for (int i = tid; i < MCENT; i += 1024) fps_idx[b * MCENT + i] = winners[i];
}

// ------------- Kernel 2: ball query + K-smallest selection (1 wave/centroid) --
__global__ __launch_bounds__(256) void ballq_kernel(const float* __restrict__ pos,
                                                    const int* __restrict__ fps_idx,
                                                    int* __restrict__ nbr,
                                                    float* __restrict__ out_pc,
                                                    float* __restrict__ out_batch) {
  const int wave = threadIdx.x >> 6;
  const int lane = threadIdx.x & 63;
  const int c = blockIdx.x * 4 + wave;   // global centroid id
  const int b = c >> 12;                 // 4096 centroids per cloud
  const float* P = pos + (size_t)b * NPTS * 3;

  const int ci = fps_idx[c];
  const float cx = P[3 * ci + 0];
  const float cy = P[3 * ci + 1];
  const float cz = P[3 * ci + 2];
  if (lane == 0) {
    out_pc[3 * c + 0] = cx;
    out_pc[3 * c + 1] = cy;
    out_pc[3 * c + 2] = cz;
    out_batch[c] = (float)b;
  }

  __shared__ unsigned long long list[4][1024];
  __shared__ int cnt[4];
  if (lane == 0) cnt[wave] = 0;

  for (int i = lane; i < NPTS; i += 64) {
    const float qx = P[3 * i + 0];
    const float qy = P[3 * i + 1];
    const float qz = P[3 * i + 2];
    const float dd = d2e(cx, cy, cz, qx, qy, qz);
    if (dd <= R2CUT) {
      int p = atomicAdd(&cnt[wave], 1);
      if (p < 1024)
        list[wave][p] = ((unsigned long long)__float_as_uint(dd) << 32)
                      | (unsigned long long)(unsigned)i;
    }
  }
  __syncthreads();

  int n = cnt[wave];
  if (n > 1024) n = 1024;

  unsigned long long loc[16];
#pragma unroll
  for (int k = 0; k < 16; ++k) {
    int i = lane + k * 64;
    loc[k] = (i < n) ? list[wave][i] : ~0ULL;
  }
  unsigned long long mv = loc[0];
#pragma unroll
  for (int k = 1; k < 16; ++k)
    if (loc[k] < mv) mv = loc[k];

  int myout = -1;
  for (int s = 0; s < 64; ++s) {
    unsigned long long wmin = mv;
#pragma unroll
    for (int off = 32; off >= 1; off >>= 1) {
      unsigned long long o = __shfl_xor(wmin, off);
      if (o < wmin) wmin = o;
    }
    if (lane == s) myout = (wmin == ~0ULL) ? -1 : (int)(unsigned)wmin;
    if (mv == wmin && wmin != ~0ULL) {
#pragma unroll
      for (int k = 0; k < 16; ++k)
        if (loc[k] == wmin) loc[k] = ~0ULL;
      mv = loc[0];
#pragma unroll
      for (int k = 1; k < 16; ++k)
        if (loc[k] < mv) mv = loc[k];
    }
  }
  nbr[c * KNBR + lane] = myout;
}

// ------------- Kernel 3: MLP (35->64 relu ->128) + masked max-pool ----------
__global__ __launch_bounds__(256) void mlp_kernel(const float* __restrict__ pos,
                                                  const float* __restrict__ x,
                                                  const int* __restrict__ fps_idx,
                                                  const int* __restrict__ nbr,
                                                  const float* __restrict__ W1,
                                                  const float* __restrict__ b1,
                                                  const float* __restrict__ W2,
                                                  const float* __restrict__ b2,
                                                  float* __restrict__ out) {
  const int c = blockIdx.x;
  const int b = c >> 12;
  const float* P = pos + (size_t)b * NPTS * 3;
  const float* X = x + (size_t)b * NPTS * FDIM;

  __shared__ float W1s[35 * 64];
  __shared__ float W2s[64 * 128];
  __shared__ float b1s[64];
  __shared__ float b2s[128];
  __shared__ float h1s[64][64];
  __shared__ float pmax[2][128];
  __shared__ int validk[64];

  const int tid = threadIdx.x;
  for (int i = tid; i < 35 * 64; i += 256) W1s[i] = W1[i];
  for (int i = tid; i < 64 * 128; i += 256) W2s[i] = W2[i];
  if (tid < 64) b1s[tid] = b1[tid];
  else if (tid < 192) b2s[tid - 64] = b2[tid - 64];

  const int ci = fps_idx[c];
  const float c5x = P[3 * ci + 0] / 0.2f;  // faithful: pos_i / r
  const float c5y = P[3 * ci + 1] / 0.2f;
  const float c5z = P[3 * ci + 2] / 0.2f;

  const int k = tid >> 2, q = tid & 3;
  const int nk = nbr[c * KNBR + k];
  if (q == 0) validk[k] = (nk >= 0) ? 1 : 0;
  const int nkc = (nk < 0) ? 0 : nk;

  float msg[35];
  const float4* Xr = (const float4*)(X + (size_t)nkc * FDIM);
#pragma unroll
  for (int i4 = 0; i4 < 8; ++i4) {
    float4 v = Xr[i4];
    msg[i4 * 4 + 0] = v.x; msg[i4 * 4 + 1] = v.y;
    msg[i4 * 4 + 2] = v.z; msg[i4 * 4 + 3] = v.w;
  }
  msg[32] = P[3 * nkc + 0] - c5x;
  msg[33] = P[3 * nkc + 1] - c5y;
  msg[34] = P[3 * nkc + 2] - c5z;

  __syncthreads();

  float acc[16];
#pragma unroll
  for (int h = 0; h < 16; ++h) acc[h] = b1s[q * 16 + h];
#pragma unroll
  for (int i = 0; i < 35; ++i) {
    const float m = msg[i];
    const float4* wrow = (const float4*)&W1s[i * 64 + q * 16];
#pragma unroll
    for (int j4 = 0; j4 < 4; ++j4) {
      float4 w = wrow[j4];
      acc[j4 * 4 + 0] += m * w.x;
      acc[j4 * 4 + 1] += m * w.y;
      acc[j4 * 4 + 2] += m * w.z;
      acc[j4 * 4 + 3] += m * w.w;
    }
  }
#pragma unroll
  for (int h = 0; h < 16; ++h) h1s[k][q * 16 + h] = fmaxf(acc[h], 0.0f);
  __syncthreads();

  const int ch = tid & 127, half = tid >> 7;
  float w2r[64];
#pragma unroll
  for (int i = 0; i < 64; ++i) w2r[i] = W2s[i * 128 + ch];

  float mx = -INFINITY;
  for (int k2 = half * 32; k2 < half * 32 + 32; ++k2) {
    if (!validk[k2]) continue;
    float s = b2s[ch];
    const float4* hr = (const float4*)h1s[k2];
#pragma unroll
    for (int i4 = 0; i4 < 16; ++i4) {
      float4 h4 = hr[i4];
      s += h4.x * w2r[i4 * 4 + 0] + h4.y * w2r[i4 * 4 + 1]
         + h4.z * w2r[i4 * 4 + 2] + h4.w * w2r[i4 * 4 + 3];
    }
    mx = fmaxf(mx, s);
  }
  pmax[half][ch] = mx;
  __syncthreads();

  if (tid < 128) {
    float m2 = fmaxf(pmax[0][tid], pmax[1][tid]);
    out[(size_t)c * CODIM + tid] = (m2 > -INFINITY) ? m2 : 0.0f;
  }
}

extern "C" void kernel_launch(void* const* d_in, const int* in_sizes, int n_in,
                              void* d_out, int out_size, void* d_ws, size_t ws_size,
                              hipStream_t stream) {
  const float* x   = (const float*)d_in[0];
  const float* pos = (const float*)d_in[1];
  const float* W1  = (const float*)d_in[3];
  const float* b1  = (const float*)d_in[4];
  const float* W2  = (const float*)d_in[5];
  const float* b2  = (const float*)d_in[6];
  float* out = (float*)d_out;

  int* fps_idx = (int*)d_ws;                  // B*M ints = 32 KiB
  int* nbr     = (int*)d_ws + BCLD * MCENT;   // B*M*K ints = 2 MiB
  // fps scratch aliases the nbr region (fps completes before ballq writes nbr)
  float4* ws_sorted = (float4*)nbr;           // B*N float4 = 512 KiB

  float* out_pc    = out + (size_t)BCLD * MCENT * CODIM;
  float* out_batch = out_pc + (size_t)BCLD * MCENT * 3;

  hipLaunchKernelGGL(fps_kernel, dim3(BCLD), dim3(1024), 0, stream, pos, fps_idx, ws_sorted);
  hipLaunchKernelGGL(ballq_kernel, dim3(BCLD * MCENT / 4), dim3(256), 0, stream,
                     pos, fps_idx, nbr, out_pc, out_batch);
  hipLaunchKernelGGL(mlp_kernel, dim3(BCLD * MCENT), dim3(256), 0, stream,
                     pos, x, fps_idx, nbr, W1, b1, W2, b2, out);
}